// Round 4
// baseline (1426.350 us; speedup 1.0000x reference)
//
#include <hip/hip_runtime.h>
#include <stdint.h>

typedef short short8 __attribute__((ext_vector_type(8)));
typedef float floatx16 __attribute__((ext_vector_type(16)));

#define NPTS 16384
#define TILE_M 128
#define THREADS 512
#define PA 2   // A-fragment (LDS) prefetch depth
#define PB 4   // B-fragment (global/L2) prefetch depth

__device__ inline unsigned short f2bf(float f) {
  union { float f; unsigned u; } v; v.f = f;
  unsigned u = v.u;
  unsigned r = (u + 0x7fffu + ((u >> 16) & 1u)) >> 16;
  return (unsigned short)r;
}
__device__ inline float bf2f(unsigned short h) {
  union { unsigned u; float f; } v; v.u = ((unsigned)h) << 16;
  return v.f;
}

// Persistent NODE integrator, TILE_M=128: the 1 MB/eval L2 weight stream is
// amortized over 128 points (half the total L2 traffic of TILE_M=64), and
// with grid=128 each active CU gets ~2x the L2 fair-share bandwidth.
// VGPR budget: acc[4][2]=128 + bq 32 + aq 32 + misc ~= 222 <= 256 cap
// (2 waves/SIMD, 1 WG/CU by construction).
__global__ __launch_bounds__(THREADS, 1) void node_kernel(
    const float* __restrict__ x, float* __restrict__ outp,
    const unsigned short* __restrict__ wbf, const float* __restrict__ sfall,
    const float* __restrict__ w1a, const float* __restrict__ b1a,
    const float* __restrict__ b2a, const float* __restrict__ b3a,
    const float* __restrict__ w4a, const float* __restrict__ b4a,
    const float* __restrict__ w1b, const float* __restrict__ b1b,
    const float* __restrict__ b2b, const float* __restrict__ b3b,
    const float* __restrict__ w4b, const float* __restrict__ b4b)
{
  // act: 128 x 512 bf16, row pitch 520 u16 (1040 B = 65*16B -> afrag b128
  // reads land row r on bank-quad r%8 => conflict-free). 133120 B.
  __shared__ unsigned short act[TILE_M][520];
  __shared__ float pcur4[TILE_M][4];  // integrated position (float4 padded)
  __shared__ float pev4[TILE_M][4];   // stage evaluation point
  __shared__ float kac4[TILE_M][4];   // RK4 accumulator
  __shared__ float w4s[3][512];       // staged W4 (fp32), 6144 B

  const int tid = threadIdx.x;
  const int wg = blockIdx.x;
  const int m0 = wg * TILE_M;
  const int batch = wg >> 5;          // 32 WGs per batch (4096/128)
  const int lane = tid & 63;
  const int wid = tid >> 6;           // 0..7: owns cols [wid*64, wid*64+64)

  // ---- init state from x ----
  if (tid < TILE_M * 3) {
    int m = tid / 3, c = tid % 3;
    float v = x[m0 * 3 + tid];
    pcur4[m][c] = v;
    pev4[m][c] = v;
  }
  __syncthreads();

  // A-frag (32x32x16): lane holds act[rb*32+(lane&31)][kt*16 + (lane>>5)*8 ..+8]
  // B-frag: fragment-major wf[((kt*16 + nt)*64 + lane)*8]
  const int aBase = (lane & 31) * 1040 + (lane >> 5) * 16;   // bytes
  const char* actB = (const char*)&act[0][0];
  const int bcol0 = (wid * 2 + 0) * 64 + lane;               // short8 index
  const int bcol1 = (wid * 2 + 1) * 64 + lane;

  const float dt = 0.05f;

  #pragma unroll 1
  for (int f = 0; f < 2; ++f) {
    const float* w1 = f ? w1b : w1a;
    const float* b1v = f ? b1b : b1a;
    const float* b2v = f ? b2b : b2a;
    const float* b3v = f ? b3b : b3a;
    const float* w4 = f ? w4b : w4a;
    const float* b4v = f ? b4b : b4a;
    const short8* w2p0 = (const short8*)(wbf + (size_t)(f * 2 + 0) * 262144) + bcol0;
    const short8* w2p1 = (const short8*)(wbf + (size_t)(f * 2 + 0) * 262144) + bcol1;
    const short8* w3p0 = (const short8*)(wbf + (size_t)(f * 2 + 1) * 262144) + bcol0;
    const short8* w3p1 = (const short8*)(wbf + (size_t)(f * 2 + 1) * 262144) + bcol1;

    // hoisted per-block-f phase-1 / phase-4 constants
    const float ww0 = w1[tid * 3 + 0], ww1 = w1[tid * 3 + 1], ww2 = w1[tid * 3 + 2];
    const float bb = b1v[tid];
    const float ss = sfall[f * 2048 + batch * 512 + tid];
    const float b40 = b4v[0], b41 = b4v[1], b42 = b4v[2];

    // stage W4 (3x512 fp32) into LDS once per f-block
    for (int i = tid; i < 1536; i += THREADS) ((float*)w4s)[i] = w4[i];
    __syncthreads();

    #pragma unroll 1
    for (int st = 0; st < 4; ++st) {
      #pragma unroll 1
      for (int stage = 0; stage < 4; ++stage) {
        // issue s=0 B prefetch before phase 1: restart the L2 weight stream
        // while the VALU phase runs (no dependency on act)
        short8 bq0[PB], bq1[PB];
        #pragma unroll
        for (int i = 0; i < PB - 1; ++i) {
          bq0[i] = w2p0[i * 1024];
          bq1[i] = w2p1[i * 1024];
        }

        // ---- phase 1: act = relu(pev@W1.T + b1) * sf ----
        #pragma unroll 4
        for (int m = 0; m < TILE_M; ++m) {
          const float4 pv = *(const float4*)&pev4[m][0];  // b128 broadcast
          float v = fmaf(pv.x, ww0, fmaf(pv.y, ww1, fmaf(pv.z, ww2, bb)));
          v = fmaxf(v, 0.f) * ss;
          act[m][tid] = f2bf(v);
        }
        __syncthreads();

        // ---- phases 2+3: two residual GEMMs, h = relu(h@W.T + b) + h ----
        for (int s = 0; s < 2; ++s) {
          const short8* bp0 = s ? w3p0 : w2p0;
          const short8* bp1 = s ? w3p1 : w2p1;
          const float* bias = s ? b3v : b2v;
          floatx16 acc[4][2] = {};
          short8 aq[4][PA];
          if (s == 1) {
            #pragma unroll
            for (int i = 0; i < PB - 1; ++i) {
              bq0[i] = bp0[i * 1024];
              bq1[i] = bp1[i * 1024];
            }
          }
          #pragma unroll
          for (int i = 0; i < PA - 1; ++i) {
            #pragma unroll
            for (int rb = 0; rb < 4; ++rb)
              aq[rb][i] = *(const short8*)(actB + aBase + rb * 33280 + i * 32);
          }

          #pragma unroll
          for (int kt = 0; kt < 32; ++kt) {
            int la = kt + PA - 1;
            if (la < 32) {
              #pragma unroll
              for (int rb = 0; rb < 4; ++rb)
                aq[rb][la % PA] = *(const short8*)(actB + aBase + rb * 33280 + la * 32);
            }
            int lb = kt + PB - 1;
            if (lb < 32) {
              bq0[lb % PB] = bp0[lb * 1024];
              bq1[lb % PB] = bp1[lb * 1024];
            }
            #pragma unroll
            for (int rb = 0; rb < 4; ++rb) {
              acc[rb][0] = __builtin_amdgcn_mfma_f32_32x32x16_bf16(aq[rb][kt % PA], bq0[kt % PB], acc[rb][0], 0, 0, 0);
              acc[rb][1] = __builtin_amdgcn_mfma_f32_32x32x16_bf16(aq[rb][kt % PA], bq1[kt % PB], acc[rb][1], 0, 0, 0);
            }
          }

          __syncthreads();   // all waves done reading act before epilogue writes
          // epilogue: C/D layout col=lane&31, row=(reg&3)+8*(reg>>2)+4*(lane>>5)
          {
            int ncol0 = (wid * 2 + 0) * 32 + (lane & 31);
            int ncol1 = (wid * 2 + 1) * 32 + (lane & 31);
            float bs0 = bias[ncol0], bs1 = bias[ncol1];
            int rbase = 4 * (lane >> 5);
            #pragma unroll
            for (int rb = 0; rb < 4; ++rb) {
              #pragma unroll
              for (int reg = 0; reg < 16; ++reg) {
                int row = rb * 32 + (reg & 3) + 8 * (reg >> 2) + rbase;
                float v = fmaxf(acc[rb][0][reg] + bs0, 0.f) + bf2f(act[row][ncol0]);
                act[row][ncol0] = f2bf(v);
                v = fmaxf(acc[rb][1][reg] + bs1, 0.f) + bf2f(act[row][ncol1]);
                act[row][ncol1] = f2bf(v);
              }
            }
          }
          __syncthreads();
        }

        // ---- phase 4: flow = tanh(act@W4.T + b4), then RK4 stage update ----
        // 4-lane groups per point; k-chunks k0=(c*4+jj)*8 read as short8 (b128,
        // aggregate-conflict-free); W4 from LDS fp32 via float4 (broadcast
        // across the 16 groups sharing jj)
        {
          int m = tid >> 2, jj = tid & 3;
          const unsigned short* arow = &act[m][0];
          float s0 = 0.f, s1 = 0.f, s2 = 0.f;
          #pragma unroll
          for (int c = 0; c < 16; ++c) {
            int k0 = (c * 4 + jj) * 8;
            short8 av = *(const short8*)(arow + k0);
            float wv[3][8];
            #pragma unroll
            for (int n = 0; n < 3; ++n) {
              *(float4*)&wv[n][0] = *(const float4*)&w4s[n][k0];
              *(float4*)&wv[n][4] = *(const float4*)&w4s[n][k0 + 4];
            }
            #pragma unroll
            for (int e = 0; e < 8; ++e) {
              float a = bf2f((unsigned short)av[e]);
              s0 = fmaf(a, wv[0][e], s0);
              s1 = fmaf(a, wv[1][e], s1);
              s2 = fmaf(a, wv[2][e], s2);
            }
          }
          s0 += __shfl_xor(s0, 1); s1 += __shfl_xor(s1, 1); s2 += __shfl_xor(s2, 1);
          s0 += __shfl_xor(s0, 2); s1 += __shfl_xor(s1, 2); s2 += __shfl_xor(s2, 2);
          if (jj < 3) {
            float sv = (jj == 0) ? s0 : ((jj == 1) ? s1 : s2);
            float bv = (jj == 0) ? b40 : ((jj == 1) ? b41 : b42);
            float fl = tanhf(sv + bv);
            float pc = pcur4[m][jj];
            if (stage == 0) {
              kac4[m][jj] = fl;
              pev4[m][jj] = fmaf(0.5f * dt, fl, pc);
            } else if (stage == 1) {
              kac4[m][jj] += 2.f * fl;
              pev4[m][jj] = fmaf(0.5f * dt, fl, pc);
            } else if (stage == 2) {
              kac4[m][jj] += 2.f * fl;
              pev4[m][jj] = fmaf(dt, fl, pc);
            } else {
              float np = fmaf(dt / 6.f, kac4[m][jj] + fl, pc);
              pcur4[m][jj] = np;
              pev4[m][jj] = np;
            }
          }
        }
        __syncthreads();
      }
    }
  }

  // ---- write final positions ----
  if (tid < TILE_M * 3) outp[m0 * 3 + tid] = pcur4[tid / 3][tid % 3];
}

// ---- setup: shuffle W (512x512 fp32 row-major, W[n][k]) into fragment-major
// bf16: dst[((kt*16 + nt)*64 + lane)*8 + j] = W[nt*32+(lane&31)][kt*16+(lane>>5)*8+j]
__global__ void setup_shuffle(const float* s0, const float* s1, const float* s2,
                              const float* s3, unsigned short* dst) {
  int idx = blockIdx.x * blockDim.x + threadIdx.x;   // 4 * 32768
  int w = idx >> 15;
  int r = idx & 32767;            // (kt*16+nt)*64 + lane
  int lane = r & 63;
  int tile = r >> 6;
  int nt = tile & 15, kt = tile >> 4;
  const float* W = (w == 0) ? s0 : (w == 1) ? s1 : (w == 2) ? s2 : s3;
  int n = nt * 32 + (lane & 31);
  int k0 = kt * 16 + (lane >> 5) * 8;
  const float* src = W + n * 512 + k0;
  unsigned short* d = dst + ((size_t)w << 18) + (size_t)r * 8;
  #pragma unroll
  for (int j = 0; j < 8; ++j) d[j] = f2bf(src[j]);
}

__global__ void setup_sf(const float* code, const float* cw1, const float* cb1,
                         const float* cw2, const float* cb2, float* sfout) {
  int f = blockIdx.x >> 2, b = blockIdx.x & 3;
  const float* cw = f ? cw2 : cw1;
  const float* cb = f ? cb2 : cb1;
  int j = threadIdx.x;
  const float* c = code + b * 512;
  float s = cb[j];
  for (int k = 0; k < 512; ++k) s = fmaf(c[k], cw[j * 512 + k], s);
  sfout[f * 2048 + b * 512 + j] = tanhf(s);
}

extern "C" void kernel_launch(void* const* d_in, const int* in_sizes, int n_in,
                              void* d_out, int out_size, void* d_ws, size_t ws_size,
                              hipStream_t stream) {
  const float* code = (const float*)d_in[0];
  const float* x    = (const float*)d_in[1];
  char* ws = (char*)d_ws;
  float* sf = (float*)ws;                               // 2*2048 fp32 = 16 KB
  unsigned short* wbf = (unsigned short*)(ws + 16384);  // 4 * 262144 u16 = 2 MB

  setup_shuffle<<<512, 256, 0, stream>>>((const float*)d_in[4], (const float*)d_in[6],
                                         (const float*)d_in[14], (const float*)d_in[16], wbf);
  setup_sf<<<8, 512, 0, stream>>>(code, (const float*)d_in[10], (const float*)d_in[11],
                                  (const float*)d_in[20], (const float*)d_in[21], sf);

  node_kernel<<<NPTS / TILE_M, THREADS, 0, stream>>>(x, (float*)d_out, wbf, sf,
      (const float*)d_in[2], (const float*)d_in[3], (const float*)d_in[5],
      (const float*)d_in[7], (const float*)d_in[8], (const float*)d_in[9],
      (const float*)d_in[12], (const float*)d_in[13], (const float*)d_in[15],
      (const float*)d_in[17], (const float*)d_in[18], (const float*)d_in[19]);
}

// Round 5
// 802.696 us; speedup vs baseline: 1.7769x; 1.7769x over previous
//
#include <hip/hip_runtime.h>
#include <stdint.h>

typedef short short8 __attribute__((ext_vector_type(8)));
typedef float floatx16 __attribute__((ext_vector_type(16)));

#define NPTS 16384
#define TILE_M 64
#define THREADS 1024
#define PA 2   // A-fragment (LDS) prefetch depth
#define PB 4   // B-fragment (global/L2) prefetch depth

__device__ inline unsigned short f2bf(float f) {
  union { float f; unsigned u; } v; v.f = f;
  unsigned u = v.u;
  unsigned r = (u + 0x7fffu + ((u >> 16) & 1u)) >> 16;
  return (unsigned short)r;
}
__device__ inline float bf2f(unsigned short h) {
  union { unsigned u; float f; } v; v.u = ((unsigned)h) << 16;
  return v.f;
}

// Persistent NODE integrator: 1024 threads (16 waves) per WG, TILE_M=64,
// 256 WGs -> 16 waves/CU = 4 waves/SIMD for latency hiding (the measured
// bottleneck: dependent chains + LDS/global latency at 2 waves/SIMD).
// Each wave owns ONE 32-col output block per GEMM (acc=32 regs, 1 B-stream).
// __launch_bounds__(1024,1): a 1024-thread block needs 16 resident waves,
// forcing the <=128 VGPR budget under either launch_bounds semantics.
__global__ __launch_bounds__(THREADS, 1) void node_kernel(
    const float* __restrict__ x, float* __restrict__ outp,
    const unsigned short* __restrict__ wbf, const float* __restrict__ sfall,
    const float* __restrict__ w1a, const float* __restrict__ b1a,
    const float* __restrict__ b2a, const float* __restrict__ b3a,
    const float* __restrict__ w4a, const float* __restrict__ b4a,
    const float* __restrict__ w1b, const float* __restrict__ b1b,
    const float* __restrict__ b2b, const float* __restrict__ b3b,
    const float* __restrict__ w4b, const float* __restrict__ b4b)
{
  // act: 64 x 512 bf16, row pitch 520 u16 (1040 B = 65*16B -> afrag b128
  // reads land row r on bank-quad r%8 => conflict-free). 66560 B.
  __shared__ unsigned short act[TILE_M][520];
  __shared__ float pcur4[TILE_M][4];  // integrated position (float4 padded)
  __shared__ float pev4[TILE_M][4];   // stage evaluation point
  __shared__ float kac4[TILE_M][4];   // RK4 accumulator
  __shared__ float w4s[3][512];       // staged W4 (fp32), 6144 B

  const int tid = threadIdx.x;
  const int wg = blockIdx.x;
  const int m0 = wg * TILE_M;
  const int batch = wg >> 6;          // 64 WGs per batch (4096/64)
  const int lane = tid & 63;
  const int wid = tid >> 6;           // 0..15: owns cols [wid*32, wid*32+32)

  // ---- init state from x ----
  if (tid < TILE_M * 3) {
    int m = tid / 3, c = tid % 3;
    float v = x[m0 * 3 + tid];
    pcur4[m][c] = v;
    pev4[m][c] = v;
  }
  __syncthreads();

  // A-frag (32x32x16): lane holds act[rb*32+(lane&31)][kt*16 + (lane>>5)*8 ..+8]
  // B-frag: fragment-major wf[((kt*16 + nt)*64 + lane)*8], nt = wid
  const int aBase = (lane & 31) * 1040 + (lane >> 5) * 16;   // bytes
  const char* actB = (const char*)&act[0][0];
  const int bcol = wid * 64 + lane;                          // short8 index

  // phase-1 column owned by this thread (2 threads per column, split rows)
  const int p1col = tid & 511;
  const int p1r0 = (tid >> 9) * 32;

  const float dt = 0.05f;

  #pragma unroll 1
  for (int f = 0; f < 2; ++f) {
    const float* w1 = f ? w1b : w1a;
    const float* b1v = f ? b1b : b1a;
    const float* b2v = f ? b2b : b2a;
    const float* b3v = f ? b3b : b3a;
    const float* w4 = f ? w4b : w4a;
    const float* b4v = f ? b4b : b4a;
    const short8* w2p = (const short8*)(wbf + (size_t)(f * 2 + 0) * 262144) + bcol;
    const short8* w3p = (const short8*)(wbf + (size_t)(f * 2 + 1) * 262144) + bcol;

    // hoisted per-block-f phase-1 / phase-4 constants
    const float ww0 = w1[p1col * 3 + 0], ww1 = w1[p1col * 3 + 1], ww2 = w1[p1col * 3 + 2];
    const float bb = b1v[p1col];
    const float ss = sfall[f * 2048 + batch * 512 + p1col];
    const float b40 = b4v[0], b41 = b4v[1], b42 = b4v[2];

    // stage W4 (3x512 fp32) into LDS once per f-block
    for (int i = tid; i < 1536; i += THREADS) ((float*)w4s)[i] = w4[i];
    __syncthreads();

    #pragma unroll 1
    for (int st = 0; st < 4; ++st) {
      #pragma unroll 1
      for (int stage = 0; stage < 4; ++stage) {
        // issue s=0 B prefetch before phase 1: restart the L2 weight stream
        // while the VALU phase runs (no dependency on act)
        short8 bq[PB];
        #pragma unroll
        for (int i = 0; i < PB - 1; ++i) bq[i] = w2p[i * 1024];

        // ---- phase 1: act = relu(pev@W1.T + b1) * sf ----
        // rows p1r0..p1r0+31, column p1col; pev read is a b128 broadcast
        #pragma unroll 4
        for (int mi = 0; mi < 32; ++mi) {
          int m = p1r0 + mi;
          const float4 pv = *(const float4*)&pev4[m][0];
          float v = fmaf(pv.x, ww0, fmaf(pv.y, ww1, fmaf(pv.z, ww2, bb)));
          v = fmaxf(v, 0.f) * ss;
          act[m][p1col] = f2bf(v);
        }
        __syncthreads();

        // ---- phases 2+3: two residual GEMMs, h = relu(h@W.T + b) + h ----
        for (int s = 0; s < 2; ++s) {
          const short8* bp = s ? w3p : w2p;
          const float* bias = s ? b3v : b2v;
          floatx16 acc0{}, acc1{};
          short8 aq0[PA], aq1[PA];
          if (s == 1) {
            #pragma unroll
            for (int i = 0; i < PB - 1; ++i) bq[i] = bp[i * 1024];
          }
          #pragma unroll
          for (int i = 0; i < PA - 1; ++i) {
            aq0[i] = *(const short8*)(actB + aBase + i * 32);
            aq1[i] = *(const short8*)(actB + aBase + 33280 + i * 32);
          }

          #pragma unroll
          for (int kt = 0; kt < 32; ++kt) {
            int la = kt + PA - 1;
            if (la < 32) {
              aq0[la % PA] = *(const short8*)(actB + aBase + la * 32);
              aq1[la % PA] = *(const short8*)(actB + aBase + 33280 + la * 32);
            }
            int lb = kt + PB - 1;
            if (lb < 32) bq[lb % PB] = bp[lb * 1024];
            acc0 = __builtin_amdgcn_mfma_f32_32x32x16_bf16(aq0[kt % PA], bq[kt % PB], acc0, 0, 0, 0);
            acc1 = __builtin_amdgcn_mfma_f32_32x32x16_bf16(aq1[kt % PA], bq[kt % PB], acc1, 0, 0, 0);
          }

          __syncthreads();   // all waves done reading act before epilogue writes
          // epilogue: C/D layout col=lane&31, row=(reg&3)+8*(reg>>2)+4*(lane>>5)
          // Batch the residual LDS reads first (independent, pipelined), then
          // compute+write. Each (row,ncol) is touched by exactly one thread.
          {
            int ncol = wid * 32 + (lane & 31);
            float bs = bias[ncol];
            int rbase = 4 * (lane >> 5);
            float r0[16], r1[16];
            #pragma unroll
            for (int reg = 0; reg < 16; ++reg) {
              int row = (reg & 3) + 8 * (reg >> 2) + rbase;
              r0[reg] = bf2f(act[row][ncol]);
              r1[reg] = bf2f(act[32 + row][ncol]);
            }
            #pragma unroll
            for (int reg = 0; reg < 16; ++reg) {
              int row = (reg & 3) + 8 * (reg >> 2) + rbase;
              float v = fmaxf(acc0[reg] + bs, 0.f) + r0[reg];
              act[row][ncol] = f2bf(v);
              v = fmaxf(acc1[reg] + bs, 0.f) + r1[reg];
              act[32 + row][ncol] = f2bf(v);
            }
          }
          __syncthreads();
        }

        // ---- phase 4: flow = tanh(act@W4.T + b4), then RK4 stage update ----
        // 16-lane groups per point; 4 chunks of short8 (b128 act reads);
        // W4 from LDS fp32 via float4 (broadcast across groups sharing jj)
        {
          int m = tid >> 4, jj = tid & 15;
          const unsigned short* arow = &act[m][0];
          float s0 = 0.f, s1 = 0.f, s2 = 0.f;
          #pragma unroll
          for (int c = 0; c < 4; ++c) {
            int k0 = (c * 16 + jj) * 8;
            short8 av = *(const short8*)(arow + k0);
            float wv[3][8];
            #pragma unroll
            for (int n = 0; n < 3; ++n) {
              *(float4*)&wv[n][0] = *(const float4*)&w4s[n][k0];
              *(float4*)&wv[n][4] = *(const float4*)&w4s[n][k0 + 4];
            }
            #pragma unroll
            for (int e = 0; e < 8; ++e) {
              float a = bf2f((unsigned short)av[e]);
              s0 = fmaf(a, wv[0][e], s0);
              s1 = fmaf(a, wv[1][e], s1);
              s2 = fmaf(a, wv[2][e], s2);
            }
          }
          s0 += __shfl_xor(s0, 1); s1 += __shfl_xor(s1, 1); s2 += __shfl_xor(s2, 1);
          s0 += __shfl_xor(s0, 2); s1 += __shfl_xor(s1, 2); s2 += __shfl_xor(s2, 2);
          s0 += __shfl_xor(s0, 4); s1 += __shfl_xor(s1, 4); s2 += __shfl_xor(s2, 4);
          s0 += __shfl_xor(s0, 8); s1 += __shfl_xor(s1, 8); s2 += __shfl_xor(s2, 8);
          if (jj < 3) {
            float sv = (jj == 0) ? s0 : ((jj == 1) ? s1 : s2);
            float bv = (jj == 0) ? b40 : ((jj == 1) ? b41 : b42);
            float fl = tanhf(sv + bv);
            float pc = pcur4[m][jj];
            if (stage == 0) {
              kac4[m][jj] = fl;
              pev4[m][jj] = fmaf(0.5f * dt, fl, pc);
            } else if (stage == 1) {
              kac4[m][jj] += 2.f * fl;
              pev4[m][jj] = fmaf(0.5f * dt, fl, pc);
            } else if (stage == 2) {
              kac4[m][jj] += 2.f * fl;
              pev4[m][jj] = fmaf(dt, fl, pc);
            } else {
              float np = fmaf(dt / 6.f, kac4[m][jj] + fl, pc);
              pcur4[m][jj] = np;
              pev4[m][jj] = np;
            }
          }
        }
        __syncthreads();
      }
    }
  }

  // ---- write final positions ----
  if (tid < TILE_M * 3) outp[m0 * 3 + tid] = pcur4[tid / 3][tid % 3];
}

// ---- setup: shuffle W (512x512 fp32 row-major, W[n][k]) into fragment-major
// bf16: dst[((kt*16 + nt)*64 + lane)*8 + j] = W[nt*32+(lane&31)][kt*16+(lane>>5)*8+j]
__global__ void setup_shuffle(const float* s0, const float* s1, const float* s2,
                              const float* s3, unsigned short* dst) {
  int idx = blockIdx.x * blockDim.x + threadIdx.x;   // 4 * 32768
  int w = idx >> 15;
  int r = idx & 32767;            // (kt*16+nt)*64 + lane
  int lane = r & 63;
  int tile = r >> 6;
  int nt = tile & 15, kt = tile >> 4;
  const float* W = (w == 0) ? s0 : (w == 1) ? s1 : (w == 2) ? s2 : s3;
  int n = nt * 32 + (lane & 31);
  int k0 = kt * 16 + (lane >> 5) * 8;
  const float* src = W + n * 512 + k0;
  unsigned short* d = dst + ((size_t)w << 18) + (size_t)r * 8;
  #pragma unroll
  for (int j = 0; j < 8; ++j) d[j] = f2bf(src[j]);
}

__global__ void setup_sf(const float* code, const float* cw1, const float* cb1,
                         const float* cw2, const float* cb2, float* sfout) {
  int f = blockIdx.x >> 2, b = blockIdx.x & 3;
  const float* cw = f ? cw2 : cw1;
  const float* cb = f ? cb2 : cb1;
  int j = threadIdx.x;
  const float* c = code + b * 512;
  float s = cb[j];
  for (int k = 0; k < 512; ++k) s = fmaf(c[k], cw[j * 512 + k], s);
  sfout[f * 2048 + b * 512 + j] = tanhf(s);
}

extern "C" void kernel_launch(void* const* d_in, const int* in_sizes, int n_in,
                              void* d_out, int out_size, void* d_ws, size_t ws_size,
                              hipStream_t stream) {
  const float* code = (const float*)d_in[0];
  const float* x    = (const float*)d_in[1];
  char* ws = (char*)d_ws;
  float* sf = (float*)ws;                               // 2*2048 fp32 = 16 KB
  unsigned short* wbf = (unsigned short*)(ws + 16384);  // 4 * 262144 u16 = 2 MB

  setup_shuffle<<<512, 256, 0, stream>>>((const float*)d_in[4], (const float*)d_in[6],
                                         (const float*)d_in[14], (const float*)d_in[16], wbf);
  setup_sf<<<8, 512, 0, stream>>>(code, (const float*)d_in[10], (const float*)d_in[11],
                                  (const float*)d_in[20], (const float*)d_in[21], sf);

  node_kernel<<<NPTS / TILE_M, THREADS, 0, stream>>>(x, (float*)d_out, wbf, sf,
      (const float*)d_in[2], (const float*)d_in[3], (const float*)d_in[5],
      (const float*)d_in[7], (const float*)d_in[8], (const float*)d_in[9],
      (const float*)d_in[12], (const float*)d_in[13], (const float*)d_in[15],
      (const float*)d_in[17], (const float*)d_in[18], (const float*)d_in[19]);
}